// Round 3
// baseline (11576.633 us; speedup 1.0000x reference)
//
#include <hip/hip_runtime.h>
#include <hip/hip_bf16.h>

// Problem constants (LiftSplatBEV): B=2, N=6, C=64, HF=112, WF=200, D=64, BEV 200x200
#define BB   2
#define NN   6
#define CCH  64
#define HFE  112
#define WFE  200
#define DDE  64
#define HWF  (HFE*WFE)      // 22400 feature pixels
#define BEVH 200
#define BEVW 200
#define HWB  (BEVH*BEVW)    // 40000 BEV cells
#define ACC_ELEMS ((size_t)BB*CCH*HWB)   // 5,120,000 floats = 20.48 MB

// One thread per (bn, p) slot. Ray->ground->BEV bilinear splat of
// feat[bn,:,p] * conf[bn,p] into acc[b,:,cell], summed over the 6 cams of b.
__global__ __launch_bounds__(256) void splat_kernel(
    const float* __restrict__ feat,    // [12,64,22400] fp32
    const float* __restrict__ depth,   // [12,64,22400] fp32
    const float* __restrict__ I_inv,   // [12,3,3] fp32
    const float* __restrict__ E_inv,   // [12,4,4] fp32
    const float* __restrict__ Vm,      // [3,3] fp32
    float* __restrict__ acc)           // [2,64,40000] fp32
{
    const int bn = blockIdx.y;
    const int p  = blockIdx.x * blockDim.x + threadIdx.x;
    if (p >= HWF) return;
    const int b = bn / NN;

    // ---- geometry pixel: bug-faithful w-outer flatten: u = p/112, v = p%112
    const float u = (float)(p / HFE);
    const float v = (float)(p % HFE);

    const float* Ii = I_inv + bn * 9;
    const float* Ei = E_inv + bn * 16;

    // cam = I_inv @ [u, v, 1]
    float cx = Ii[0] * u + Ii[1] * v + Ii[2];
    float cy = Ii[3] * u + Ii[4] * v + Ii[5];
    float cz = Ii[6] * u + Ii[7] * v + Ii[8];

    // d = E_inv @ [cam; 1]  (includes translation -- bug-faithful)
    float tx = Ei[3],  ty = Ei[7],  tz = Ei[11];
    float dx = Ei[0] * cx + Ei[1] * cy + Ei[2]  * cz + tx;
    float dy = Ei[4] * cx + Ei[5] * cy + Ei[6]  * cz + ty;
    float dz = Ei[8] * cx + Ei[9] * cy + Ei[10] * cz + tz;

    // ray-ground intersection (z = 0 plane)
    float s  = -tz / fmaxf(dz, 1e-6f);
    float ex = tx + dx * s;
    float ey = ty + dy * s;

    // ego -> BEV pixel via V
    float prx = Vm[0] * ex + Vm[1] * ey + Vm[2];
    float pry = Vm[3] * ex + Vm[4] * ey + Vm[5];
    float prz = Vm[6] * ex + Vm[7] * ey + Vm[8];
    float den = fmaxf(prz, 1e-7f);
    float bx = prx / den;
    float by = pry / den;

    // bug-faithful gx->px roundtrip, same association order as reference
    float gx = bx / (float)(BEVW - 1) * 2.0f - 1.0f;
    float gy = by / (float)(BEVH - 1) * 2.0f - 1.0f;
    float px = (gx + 1.0f) * (float)(BEVW - 1) / 2.0f;
    float py = (gy + 1.0f) * (float)(BEVH - 1) / 2.0f;

    float x0f = fminf(fmaxf(floorf(px), 0.0f), (float)(BEVW - 1));
    float y0f = fminf(fmaxf(floorf(py), 0.0f), (float)(BEVH - 1));
    float x1f = fminf(fmaxf(x0f + 1.0f, 0.0f), (float)(BEVW - 1));
    float y1f = fminf(fmaxf(y0f + 1.0f, 0.0f), (float)(BEVH - 1));

    // Clipped-at-far-edge slots: corner pairs land on coincident cells with
    // exactly-opposite fp weights ((x1-px) == -(px-x0) exactly when x0==x1),
    // so they cancel exactly in the fp64 np reference. Skip them instead of
    // pushing +-1e6..1e12 transients through fp32 atomics (which would leave
    // O(ulp) residues the fp64 reference does not have).
    if (x0f == x1f || y0f == y1f) return;

    // conf = max over D of depth_prob[bn, :, p]   (h-outer flat index p)
    const float* dp = depth + (size_t)bn * DDE * HWF + p;
    float conf = dp[0];
#pragma unroll 8
    for (int d = 1; d < DDE; ++d)
        conf = fmaxf(conf, dp[(size_t)d * HWF]);

    float wx0 = x1f - px, wx1 = px - x0f;
    float wy0 = y1f - py, wy1 = py - y0f;
    float w00 = wx0 * wy0 * conf;
    float w10 = wx1 * wy0 * conf;
    float w01 = wx0 * wy1 * conf;
    float w11 = wx1 * wy1 * conf;

    int x0 = (int)x0f, x1 = (int)x1f, y0 = (int)y0f, y1 = (int)y1f;
    int i00 = y0 * BEVW + x0;
    int i10 = y0 * BEVW + x1;
    int i01 = y1 * BEVW + x0;
    int i11 = y1 * BEVW + x1;

    float* base = acc + (size_t)b * CCH * HWB;
    const float* fp_ = feat + (size_t)bn * CCH * HWF + p;

#pragma unroll 4
    for (int c = 0; c < CCH; ++c) {
        float f = fp_[(size_t)c * HWF];
        float* cell = base + (size_t)c * HWB;
        atomicAdd(cell + i00, f * w00);
        atomicAdd(cell + i10, f * w10);
        atomicAdd(cell + i01, f * w01);
        atomicAdd(cell + i11, f * w11);
    }
}

__global__ __launch_bounds__(256) void finalize_kernel(
    const float* __restrict__ acc, float* __restrict__ out)
{
    size_t i = (size_t)blockIdx.x * blockDim.x + threadIdx.x;
    if (i >= ACC_ELEMS) return;
    out[i] = acc[i] * (1.0f / 6.0f);
}

extern "C" void kernel_launch(void* const* d_in, const int* in_sizes, int n_in,
                              void* d_out, int out_size, void* d_ws, size_t ws_size,
                              hipStream_t stream) {
    const float* feat  = (const float*)d_in[0];
    const float* depth = (const float*)d_in[1];
    const float* I_inv = (const float*)d_in[2];
    const float* E_inv = (const float*)d_in[3];
    const float* Vm    = (const float*)d_in[4];
    float* acc = (float*)d_ws;   // 20.48 MB fp32 accumulator
    float* out = (float*)d_out;

    hipMemsetAsync(acc, 0, ACC_ELEMS * sizeof(float), stream);

    dim3 grid((HWF + 255) / 256, BB * NN);
    splat_kernel<<<grid, 256, 0, stream>>>(feat, depth, I_inv, E_inv, Vm, acc);

    finalize_kernel<<<((ACC_ELEMS + 255) / 256), 256, 0, stream>>>(acc, out);
}

// Round 4
// 1871.594 us; speedup vs baseline: 6.1854x; 6.1854x over previous
//
#include <hip/hip_runtime.h>

// LiftSplatBEV: B=2, N=6, C=64, HF=112, WF=200, D=64, BEV 200x200
#define BB   2
#define NN   6
#define CCH  64
#define HFE  112
#define WFE  200
#define DDE  64
#define HWF  (HFE*WFE)      // 22400 feature pixels (= 350 * 64)
#define BEVH 200
#define BEVW 200
#define HWB  (BEVH*BEVW)    // 40000 BEV cells (= 625 * 64)
#define ACC_ELEMS ((size_t)BB*HWB*CCH)   // 5,120,000 floats, channel-LAST [b][cell][c]

// Block = 256 threads (4 waves) handles 64 consecutive slots p for one camera bn.
// Phase A: stage feat tile [64c x 64p] transposed into LDS (lane=channel layout),
//          and cooperatively compute conf[slot] = max_d depth[bn,d,p] (wave w
//          covers d in [16w,16w+16), coalesced along p).
// Phase B: wave w processes slots [16w,16w+16); all 64 lanes redundantly compute
//          the slot's ray->ground->BEV geometry (wave-uniform VALU), then lane=c
//          issues 4 coalesced atomics into channel-last acc[b][cell][c].
__global__ __launch_bounds__(256) void splat_kernel(
    const float* __restrict__ feat,    // [12,64,22400]
    const float* __restrict__ depth,   // [12,64,22400]
    const float* __restrict__ I_inv,   // [12,3,3]
    const float* __restrict__ E_inv,   // [12,4,4]
    const float* __restrict__ Vm,      // [3,3]
    float* __restrict__ acc)           // [2,40000,64] fp32, channel-last
{
    __shared__ float fshare[64][65];   // [slot][channel], +1 pad: conflict-free both ways
    __shared__ float cpart[4][64];     // per-wave partial conf max, [wave][slot]

    const int bn   = blockIdx.y;
    const int b    = bn / NN;
    const int p0   = blockIdx.x * 64;  // 22400 = 350*64, exact
    const int tid  = threadIdx.x;
    const int lane = tid & 63;
    const int wv   = tid >> 6;

    // ---- Phase A1: feat tile -> LDS transposed. Global read coalesced along p.
    const float* fbase = feat + (size_t)bn * CCH * HWF + p0;
#pragma unroll
    for (int c = wv; c < CCH; c += 4)
        fshare[lane][c] = fbase[(size_t)c * HWF + lane];   // LDS banks (lane+c)%32: conflict-free

    // ---- Phase A2: partial conf. Wave wv covers 16 depth planes, coalesced along p.
    const float* dbase = depth + (size_t)bn * DDE * HWF + p0;
    float m = dbase[(size_t)(wv * 16) * HWF + lane];
#pragma unroll
    for (int d = wv * 16 + 1; d < wv * 16 + 16; ++d)
        m = fmaxf(m, dbase[(size_t)d * HWF + lane]);
    cpart[wv][lane] = m;

    __syncthreads();

    // ---- per-camera matrices (wave-uniform)
    const float* Ii = I_inv + bn * 9;
    const float* Ei = E_inv + bn * 16;
    const float I0=Ii[0],I1=Ii[1],I2=Ii[2],I3=Ii[3],I4=Ii[4],I5=Ii[5],I6=Ii[6],I7=Ii[7],I8=Ii[8];
    const float E0=Ei[0],E1=Ei[1],E2=Ei[2],  tx=Ei[3];
    const float E4=Ei[4],E5=Ei[5],E6=Ei[6],  ty=Ei[7];
    const float E8=Ei[8],E9=Ei[9],E10=Ei[10],tz=Ei[11];
    const float V0=Vm[0],V1=Vm[1],V2=Vm[2],V3=Vm[3],V4=Vm[4],V5=Vm[5],V6=Vm[6],V7=Vm[7],V8=Vm[8];

    float* ab = acc + ((size_t)b * HWB) * CCH + lane;   // lane = channel

    for (int s = wv * 16; s < wv * 16 + 16; ++s) {
        const int p = p0 + s;
        // bug-faithful w-outer flatten: u = p/112, v = p%112
        const float u = (float)(p / HFE);
        const float v = (float)(p % HFE);

        // cam = I_inv @ [u,v,1]
        float cx = I0*u + I1*v + I2;
        float cy = I3*u + I4*v + I5;
        float cz = I6*u + I7*v + I8;
        // d = E_inv @ [cam;1] (includes translation -- bug-faithful)
        float dx = E0*cx + E1*cy + E2 *cz + tx;
        float dy = E4*cx + E5*cy + E6 *cz + ty;
        float dz = E8*cx + E9*cy + E10*cz + tz;
        // ray-ground
        float sc = -tz / fmaxf(dz, 1e-6f);
        float ex = tx + dx * sc;
        float ey = ty + dy * sc;
        // ego -> BEV via V
        float prx = V0*ex + V1*ey + V2;
        float pry = V3*ex + V4*ey + V5;
        float prz = V6*ex + V7*ey + V8;
        float den = fmaxf(prz, 1e-7f);
        float bx = prx / den;
        float by = pry / den;
        // bug-faithful gx->px roundtrip (same association order as reference)
        float gx = bx / (float)(BEVW - 1) * 2.0f - 1.0f;
        float gy = by / (float)(BEVH - 1) * 2.0f - 1.0f;
        float px = (gx + 1.0f) * (float)(BEVW - 1) / 2.0f;
        float py = (gy + 1.0f) * (float)(BEVH - 1) / 2.0f;

        float x0f = fminf(fmaxf(floorf(px), 0.0f), (float)(BEVW - 1));
        float y0f = fminf(fmaxf(floorf(py), 0.0f), (float)(BEVH - 1));
        float x1f = fminf(x0f + 1.0f, (float)(BEVW - 1));
        float y1f = fminf(y0f + 1.0f, (float)(BEVH - 1));
        // degenerate far-edge slots cancel exactly in the fp64 np ref: skip
        if (x0f == x1f || y0f == y1f) continue;

        float cf = fmaxf(fmaxf(cpart[0][s], cpart[1][s]),
                         fmaxf(cpart[2][s], cpart[3][s]));   // broadcast LDS reads

        float wx0 = x1f - px, wx1 = px - x0f;
        float wy0 = y1f - py, wy1 = py - y0f;
        float w00 = wx0*wy0*cf, w10 = wx1*wy0*cf;
        float w01 = wx0*wy1*cf, w11 = wx1*wy1*cf;

        int x0 = (int)x0f, x1 = (int)x1f, y0 = (int)y0f, y1 = (int)y1f;
        size_t i00 = (size_t)(y0 * BEVW + x0) * CCH;
        size_t i10 = (size_t)(y0 * BEVW + x1) * CCH;
        size_t i01 = (size_t)(y1 * BEVW + x0) * CCH;
        size_t i11 = (size_t)(y1 * BEVW + x1) * CCH;

        float f = fshare[s][lane];   // banks (s*65+lane)%32: conflict-free
        // 64 lanes -> 64 consecutive floats: one coalesced 256B atomic burst/corner
        atomicAdd(ab + i00, f * w00);
        atomicAdd(ab + i10, f * w10);
        atomicAdd(ab + i01, f * w01);
        atomicAdd(ab + i11, f * w11);
    }
}

// out[b][c][cell] = acc[b][cell][c] / 6 -- LDS-transposed so both global
// accesses are coalesced. Block handles a 64-cell x 64-channel tile.
__global__ __launch_bounds__(256) void finalize_kernel(
    const float* __restrict__ acc, float* __restrict__ out)
{
    __shared__ float t[64][65];
    const int b     = blockIdx.y;
    const int cell0 = blockIdx.x * 64;   // 40000 = 625*64, exact
    const int lane  = threadIdx.x & 63;
    const int r     = threadIdx.x >> 6;

    const float* abase = acc + ((size_t)b * HWB + cell0) * CCH;
#pragma unroll
    for (int cell = r; cell < 64; cell += 4)
        t[cell][lane] = abase[(size_t)cell * CCH + lane];   // lane=channel: coalesced
    __syncthreads();

    float* obase = out + (size_t)b * CCH * HWB + cell0;
#pragma unroll
    for (int c = r; c < 64; c += 4)
        obase[(size_t)c * HWB + lane] = t[lane][c] * (1.0f / 6.0f);  // lane=cell: coalesced
}

extern "C" void kernel_launch(void* const* d_in, const int* in_sizes, int n_in,
                              void* d_out, int out_size, void* d_ws, size_t ws_size,
                              hipStream_t stream) {
    const float* feat  = (const float*)d_in[0];
    const float* depth = (const float*)d_in[1];
    const float* I_inv = (const float*)d_in[2];
    const float* E_inv = (const float*)d_in[3];
    const float* Vm    = (const float*)d_in[4];
    float* acc = (float*)d_ws;   // 20.48 MB fp32 channel-last accumulator
    float* out = (float*)d_out;

    hipMemsetAsync(acc, 0, ACC_ELEMS * sizeof(float), stream);

    dim3 grid(HWF / 64, BB * NN);         // (350, 12)
    splat_kernel<<<grid, 256, 0, stream>>>(feat, depth, I_inv, E_inv, Vm, acc);

    dim3 fgrid(HWB / 64, BB);             // (625, 2)
    finalize_kernel<<<fgrid, 256, 0, stream>>>(acc, out);
}